// Round 13
// baseline (269.849 us; speedup 1.0000x reference)
//
#include <hip/hip_runtime.h>

#define N_TOK 4096
#define NH    4

typedef __attribute__((ext_vector_type(8))) short bf16x8;
typedef __attribute__((ext_vector_type(4))) short bf16x4;
typedef __attribute__((ext_vector_type(4))) float f32x4;

static constexpr float SCALE   = 0.17677669529663687f;  // 32^-0.5
static constexpr float QSCALE  = 0.25503632254435463f;  // SCALE * log2(e)
static constexpr float LAMBDA_ = 0.1f;
#define PSTRIDE 2112   // floats per (h,qt,ks) partial record (32q block)

__device__ __forceinline__ unsigned short bf_rne(float f) {
    unsigned u = __float_as_uint(f);
    u += 0x7FFF + ((u >> 16) & 1);
    return (unsigned short)(u >> 16);
}

__device__ __forceinline__ void async_copy16(const unsigned short* g, unsigned short* l) {
    __builtin_amdgcn_global_load_lds(
        (const __attribute__((address_space(1))) void*)g,
        (__attribute__((address_space(3))) void*)l, 16, 0, 0);
}

// pack two fp32 into one dword of 2 bf16 (truncate): hi halves of (b,a)
__device__ __forceinline__ unsigned pack_hi(float a, float b) {
    return __builtin_amdgcn_perm(__float_as_uint(b), __float_as_uint(a), 0x07060302u);
}

// ---------------------------------------------------------------------------
// Kernel 1: qkv projection via MFMA (R12-verified), with prep FUSED:
// w read as fp32, QSCALE + hi/lo split done in-register while building the
// A-fragments (arithmetically identical to R12's prep+load path).
// Also zeroes the 512 split-K fixup tickets (block 0) — stream order
// guarantees tickets are 0 before flash starts.
//  qA[h][n][64] bf16: {q1hi q1lo q2hi q2lo} (QSCALE folded)   kB likewise
//  vT[h][kb=key/8][dim][8keys] bf16 RNE (granule-tiled)
// ---------------------------------------------------------------------------
__global__ __launch_bounds__(256) void qkv_kernel(
    const float* __restrict__ x, const float* __restrict__ w,
    unsigned short* __restrict__ qA, unsigned short* __restrict__ kB,
    unsigned short* __restrict__ vT, unsigned* __restrict__ tickets)
{
    __shared__ __align__(16) float xf[16][132];
    __shared__ __align__(16) unsigned short xbh[16 * 136];
    __shared__ __align__(16) unsigned short xbl[16 * 136];
    __shared__ __align__(16) unsigned short qsh[2][16][64];
    __shared__ __align__(16) unsigned short ksh[2][16][64];
    __shared__ __align__(16) unsigned short vsh[2][32][16];

    const int t  = threadIdx.x;
    const int tg = blockIdx.x >> 1;
    const int rh = blockIdx.x & 1;            // row half: heads {2rh, 2rh+1}
    const int n0 = tg * 16;
    const int nhh = n0 >> 8, nw = (n0 >> 4) & 15;
    const int xbase = nhh * 2048 + nw * 64;

    if (blockIdx.x == 0) {                    // zero fixup tickets
        tickets[t] = 0u;
        tickets[t + 256] = 0u;
    }

    #pragma unroll
    for (int k = 0; k < 8; ++k) {
        int idx = t + k * 256;
        int tok = idx & 15, ch = idx >> 4;
        xf[tok][ch] = x[(size_t)ch * 32768 + xbase + tok * 2];
    }
    __syncthreads();
    #pragma unroll
    for (int k = 0; k < 8; ++k) {
        int idx = t + k * 256;
        int tok = idx & 15, ch = idx >> 4;
        float f = xf[tok][ch];
        unsigned u = __float_as_uint(f);
        float lo = f - __uint_as_float(u & 0xFFFF0000u);
        xbh[tok * 136 + ch] = (unsigned short)(u >> 16);
        xbl[tok * 136 + ch] = (unsigned short)(__float_as_uint(lo) >> 16);
    }
    __syncthreads();

    const int lane = t & 63;
    const int m    = lane & 15;
    const int quad = lane >> 4;
    const int wv   = t >> 6;

    // B-operand (tokens) fragments, shared across row-tiles
    bf16x8 Bh[4], Bl[4];
    #pragma unroll
    for (int s = 0; s < 4; ++s) {
        Bh[s] = *(const bf16x8*)&xbh[m * 136 + s * 32 + quad * 8];
        Bl[s] = *(const bf16x8*)&xbl[m * 136 + s * 32 + quad * 8];
    }

    #pragma unroll
    for (int rt = 0; rt < 3; ++rt) {
        const int R0 = rh * 192 + wv * 48 + rt * 16;
        const float sq = ((R0 % 96) < 32) ? QSCALE : 1.0f;  // tile-uniform
        const float* wp = w + (size_t)(R0 + m) * 128;
        bf16x8 Ah[4], Al[4];
        #pragma unroll
        for (int s = 0; s < 4; ++s) {
            float4 wa = *(const float4*)(wp + s * 32 + quad * 8);
            float4 wb = *(const float4*)(wp + s * 32 + quad * 8 + 4);
            float f0 = wa.x * sq, f1 = wa.y * sq, f2 = wa.z * sq, f3 = wa.w * sq;
            float f4 = wb.x * sq, f5 = wb.y * sq, f6 = wb.z * sq, f7 = wb.w * sq;
            float g0 = f0 - __uint_as_float(__float_as_uint(f0) & 0xFFFF0000u);
            float g1 = f1 - __uint_as_float(__float_as_uint(f1) & 0xFFFF0000u);
            float g2 = f2 - __uint_as_float(__float_as_uint(f2) & 0xFFFF0000u);
            float g3 = f3 - __uint_as_float(__float_as_uint(f3) & 0xFFFF0000u);
            float g4 = f4 - __uint_as_float(__float_as_uint(f4) & 0xFFFF0000u);
            float g5 = f5 - __uint_as_float(__float_as_uint(f5) & 0xFFFF0000u);
            float g6 = f6 - __uint_as_float(__float_as_uint(f6) & 0xFFFF0000u);
            float g7 = f7 - __uint_as_float(__float_as_uint(f7) & 0xFFFF0000u);
            union { unsigned u[4]; bf16x8 v; } ah, al;
            ah.u[0] = pack_hi(f0, f1); ah.u[1] = pack_hi(f2, f3);
            ah.u[2] = pack_hi(f4, f5); ah.u[3] = pack_hi(f6, f7);
            al.u[0] = pack_hi(g0, g1); al.u[1] = pack_hi(g2, g3);
            al.u[2] = pack_hi(g4, g5); al.u[3] = pack_hi(g6, g7);
            Ah[s] = ah.v; Al[s] = al.v;
        }
        f32x4 C = {0, 0, 0, 0};
        #pragma unroll
        for (int s = 0; s < 4; ++s) {
            C = __builtin_amdgcn_mfma_f32_16x16x32_bf16(Ah[s], Bh[s], C, 0, 0, 0);
            C = __builtin_amdgcn_mfma_f32_16x16x32_bf16(Al[s], Bh[s], C, 0, 0, 0);
            C = __builtin_amdgcn_mfma_f32_16x16x32_bf16(Ah[s], Bl[s], C, 0, 0, 0);
        }
        // epilogue: lane holds token m, rows R0+quad*4+i (R12-verified)
        #pragma unroll
        for (int i = 0; i < 4; ++i) {
            int R  = R0 + quad * 4 + i;
            int hh = R / 96;
            int rr = R - hh * 96;
            int hl = hh & 1;
            float f = C[i];
            if (rr < 64) {
                unsigned u = __float_as_uint(f);
                float lo = f - __uint_as_float(u & 0xFFFF0000u);
                unsigned short hi16 = (unsigned short)(u >> 16);
                unsigned short lo16 = (unsigned short)(__float_as_uint(lo) >> 16);
                int part = (rr & 31) >> 4, d = rr & 15;
                if (rr < 32) {
                    qsh[hl][m][part * 32 + d]      = hi16;
                    qsh[hl][m][part * 32 + d + 16] = lo16;
                } else {
                    ksh[hl][m][part * 32 + d]      = hi16;
                    ksh[hl][m][part * 32 + d + 16] = lo16;
                }
            } else {
                vsh[hl][rr - 64][m] = bf_rne(f);
            }
        }
    }
    __syncthreads();

    {   // qA/kB: 32 records (2 heads x 16 tok) x 8 granules of 16B
        int rec = t >> 3, ch8 = t & 7;
        int hl  = rec >> 4, i = rec & 15;
        int hh  = rh * 2 + hl;
        size_t base = ((size_t)hh * N_TOK + n0 + i) * 64 + ch8 * 8;
        *(uint4*)(qA + base) = *(const uint4*)&qsh[hl][i][ch8 * 8];
        *(uint4*)(kB + base) = *(const uint4*)&ksh[hl][i][ch8 * 8];
    }
    if (t < 128) {  // vT granule-tiled: [h][kb][dim][8]
        int hl = t >> 6, d = (t >> 1) & 31, half = t & 1;
        int hh = rh * 2 + hl;
        int kb = (n0 >> 3) + half;
        *(uint4*)(vT + (size_t)hh * 131072 + kb * 256 + d * 8) =
            *(const uint4*)&vsh[hl][d][half * 8];
    }
}

// ---------------------------------------------------------------------------
// Kernel 2: MFMA flash diff-attention v7 (compute VERBATIM from R11/R12,
// 64.5us) + split-K last-block fixup FUSED (replaces merge kernel):
// store partial -> __threadfence (device) -> ticket atomicAdd; the second
// arrival re-reads both records and writes the final output tile.
// ---------------------------------------------------------------------------
__global__ __launch_bounds__(256, 4) void flash_kernel(
    const unsigned short* __restrict__ qA, const unsigned short* __restrict__ kB,
    const unsigned short* __restrict__ vT, float* __restrict__ parts,
    unsigned* __restrict__ tickets, float* __restrict__ out)
{
    __shared__ __align__(16) unsigned short kv_sh[2][6144]; // 2 x 12 KB (K 8K + V 4K)
    __shared__ float Obuf[2][2][16][32];                    // [qt][br][r][d] 8 KB
    __shared__ float lbuf[2][2][16];
    __shared__ unsigned done_flag;

    const int t    = threadIdx.x;
    const int w    = t >> 6;
    const int lane = t & 63;
    const int m    = lane & 15;
    const int quad = lane >> 4;
    const int ks   = blockIdx.x & 1;
    const int qt   = (blockIdx.x >> 1) & 127;
    const int h    = blockIdx.x >> 8;
    const int qtile = w >> 1;                 // 0..1
    const int kh    = w & 1;                  // key half within tile
    const int qbase = qt * 32;

    const unsigned short* kBh = kB + (size_t)h * N_TOK * 64;
    const unsigned short* vTh = vT + (size_t)h * 131072;
    const int key0 = ks * 2048;

    auto stage = [&](int tile, int b) {
        const unsigned short* kben = kBh + (size_t)(key0 + tile * 64) * 64;
        const unsigned short* vben = vTh + (size_t)((key0 >> 3) + tile * 8) * 256;
        #pragma unroll
        for (int i = 0; i < 3; ++i) {
            int s = i * 256 + t;              // 0..767
            const unsigned short* src;
            if (s < 512) {                    // K: rec ml (0..63), XOR granule
                int ml = s >> 3, p = s & 7, c = p ^ (ml & 7);
                src = kben + ml * 64 + c * 8;
            } else {                          // V: granule (kb_l, dim)
                int s2 = s - 512;
                int kb_l = s2 >> 5, d = s2 & 31;
                src = vben + kb_l * 256 + d * 8;
            }
            async_copy16(src, &kv_sh[b][s * 8]);
        }
    };

    stage(0, 0);

    for (int i = t; i < 2048; i += 256) ((float*)Obuf)[i] = 0.f;
    if (t < 64) ((float*)lbuf)[t] = 0.f;

    const unsigned short* qrec = qA + (size_t)(h * N_TOK + qbase + qtile * 16 + m) * 64;
    const bf16x8 zz = {0,0,0,0,0,0,0,0};
    bf16x8 Bq1h = *(const bf16x8*)(qrec + (quad & 1) * 8);
    bf16x8 Bq2h = *(const bf16x8*)(qrec + 32 + (quad & 1) * 8);
    bf16x8 Bq1l = (quad < 2) ? *(const bf16x8*)(qrec + 16 + quad * 8) : zz;
    bf16x8 Bq2l = (quad < 2) ? *(const bf16x8*)(qrec + 48 + quad * 8) : zz;

    f32x4 O1a = {0,0,0,0}, O1b = {0,0,0,0}, O2a = {0,0,0,0}, O2b = {0,0,0,0};
    float l1 = 0.f, l2 = 0.f;

    const int ml0 = kh * 32 + m, ml1 = ml0 + 16;
    const int a1o0 = ml0 * 64 + ((quad)     ^ (ml0 & 7)) * 8;
    const int a2o0 = ml0 * 64 + ((4 + quad) ^ (ml0 & 7)) * 8;
    const int a1o1 = ml1 * 64 + ((quad)     ^ (ml1 & 7)) * 8;
    const int a2o1 = ml1 * 64 + ((4 + quad) ^ (ml1 & 7)) * 8;
    const int kbl0 = kh * 4 + (quad >> 1);
    const int v0o0 = 4096 + (kbl0 * 32 + m)      * 8 + (quad & 1) * 4;
    const int v1o0 = 4096 + (kbl0 * 32 + 16 + m) * 8 + (quad & 1) * 4;
    const int v0o1 = v0o0 + 512;
    const int v1o1 = v1o0 + 512;

    for (int tile = 0; tile < 32; ++tile) {
        const int b = tile & 1;
        __syncthreads();
        if (tile + 1 < 32) stage(tile + 1, b ^ 1);

        const unsigned short* buf = kv_sh[b];
        bf16x8 K1_0 = *(const bf16x8*)(buf + a1o0);
        bf16x8 K2_0 = *(const bf16x8*)(buf + a2o0);
        bf16x8 K1_1 = *(const bf16x8*)(buf + a1o1);
        bf16x8 K2_1 = *(const bf16x8*)(buf + a2o1);

        f32x4 sA1 = {0,0,0,0}, sA2 = {0,0,0,0};
        f32x4 sB1 = {0,0,0,0}, sB2 = {0,0,0,0};
        sA1 = __builtin_amdgcn_mfma_f32_16x16x32_bf16(K1_0, Bq1h, sA1, 0, 0, 0);
        sB1 = __builtin_amdgcn_mfma_f32_16x16x32_bf16(K1_1, Bq1h, sB1, 0, 0, 0);
        sA1 = __builtin_amdgcn_mfma_f32_16x16x32_bf16(K1_0, Bq1l, sA1, 0, 0, 0);
        sB1 = __builtin_amdgcn_mfma_f32_16x16x32_bf16(K1_1, Bq1l, sB1, 0, 0, 0);
        sA2 = __builtin_amdgcn_mfma_f32_16x16x32_bf16(K2_0, Bq2h, sA2, 0, 0, 0);
        sB2 = __builtin_amdgcn_mfma_f32_16x16x32_bf16(K2_1, Bq2h, sB2, 0, 0, 0);
        sA2 = __builtin_amdgcn_mfma_f32_16x16x32_bf16(K2_0, Bq2l, sA2, 0, 0, 0);
        sB2 = __builtin_amdgcn_mfma_f32_16x16x32_bf16(K2_1, Bq2l, sB2, 0, 0, 0);

        float pa0 = __builtin_amdgcn_exp2f(sA1[0]), pa1 = __builtin_amdgcn_exp2f(sA1[1]);
        float pa2 = __builtin_amdgcn_exp2f(sA1[2]), pa3 = __builtin_amdgcn_exp2f(sA1[3]);
        float pb0 = __builtin_amdgcn_exp2f(sB1[0]), pb1 = __builtin_amdgcn_exp2f(sB1[1]);
        float pb2 = __builtin_amdgcn_exp2f(sB1[2]), pb3 = __builtin_amdgcn_exp2f(sB1[3]);
        float qa0 = __builtin_amdgcn_exp2f(sA2[0]), qa1 = __builtin_amdgcn_exp2f(sA2[1]);
        float qa2 = __builtin_amdgcn_exp2f(sA2[2]), qa3 = __builtin_amdgcn_exp2f(sA2[3]);
        float qb0 = __builtin_amdgcn_exp2f(sB2[0]), qb1 = __builtin_amdgcn_exp2f(sB2[1]);
        float qb2 = __builtin_amdgcn_exp2f(sB2[2]), qb3 = __builtin_amdgcn_exp2f(sB2[3]);
        l1 += (pa0 + pa1) + (pa2 + pa3) + (pb0 + pb1) + (pb2 + pb3);
        l2 += (qa0 + qa1) + (qa2 + qa3) + (qb0 + qb1) + (qb2 + qb3);
        union { unsigned u[2]; bf16x4 v; } cA1, cB1, cA2, cB2;
        cA1.u[0] = pack_hi(pa0, pa1); cA1.u[1] = pack_hi(pa2, pa3);
        cB1.u[0] = pack_hi(pb0, pb1); cB1.u[1] = pack_hi(pb2, pb3);
        cA2.u[0] = pack_hi(qa0, qa1); cA2.u[1] = pack_hi(qa2, qa3);
        cB2.u[0] = pack_hi(qb0, qb1); cB2.u[1] = pack_hi(qb2, qb3);

        bf16x4 V00 = *(const bf16x4*)(buf + v0o0);
        bf16x4 V10 = *(const bf16x4*)(buf + v1o0);
        bf16x4 V01 = *(const bf16x4*)(buf + v0o1);
        bf16x4 V11 = *(const bf16x4*)(buf + v1o1);

        O1a = __builtin_amdgcn_mfma_f32_16x16x16bf16_1k(cA1.v, V00, O1a, 0, 0, 0);
        O1b = __builtin_amdgcn_mfma_f32_16x16x16bf16_1k(cA1.v, V10, O1b, 0, 0, 0);
        O2a = __builtin_amdgcn_mfma_f32_16x16x16bf16_1k(cA2.v, V00, O2a, 0, 0, 0);
        O2b = __builtin_amdgcn_mfma_f32_16x16x16bf16_1k(cA2.v, V10, O2b, 0, 0, 0);
        O1a = __builtin_amdgcn_mfma_f32_16x16x16bf16_1k(cB1.v, V01, O1a, 0, 0, 0);
        O1b = __builtin_amdgcn_mfma_f32_16x16x16bf16_1k(cB1.v, V11, O1b, 0, 0, 0);
        O2a = __builtin_amdgcn_mfma_f32_16x16x16bf16_1k(cB2.v, V01, O2a, 0, 0, 0);
        O2b = __builtin_amdgcn_mfma_f32_16x16x16bf16_1k(cB2.v, V11, O2b, 0, 0, 0);
    }

    l1 += __shfl_xor(l1, 16, 64); l1 += __shfl_xor(l1, 32, 64);
    l2 += __shfl_xor(l2, 16, 64); l2 += __shfl_xor(l2, 32, 64);
    if (lane < 16) {
        atomicAdd(&lbuf[qtile][0][m], l1);
        atomicAdd(&lbuf[qtile][1][m], l2);
    }
    #pragma unroll
    for (int i = 0; i < 4; ++i) {
        int r = quad * 4 + i;
        atomicAdd(&Obuf[qtile][0][r][m],      O1a[i]);
        atomicAdd(&Obuf[qtile][0][r][16 + m], O1b[i]);
        atomicAdd(&Obuf[qtile][1][r][m],      O2a[i]);
        atomicAdd(&Obuf[qtile][1][r][16 + m], O2b[i]);
    }
    __syncthreads();

    // store partial record: [O1 1024][O2 1024][l1 32][l2 32]
    float* dst = parts + (size_t)((h * 128 + qt) * 2 + ks) * PSTRIDE;
    for (int i = t; i < 1024; i += 256) {
        int r = i >> 5, d = i & 31;
        int qtl = r >> 4, rl = r & 15;
        dst[i]        = Obuf[qtl][0][rl][d];
        dst[1024 + i] = Obuf[qtl][1][rl][d];
    }
    if (t < 32) {
        int qtl = t >> 4, rl = t & 15;
        dst[2048 + t] = lbuf[qtl][0][rl];
        dst[2080 + t] = lbuf[qtl][1][rl];
    }

    // ---- split-K fixup: second-arriving block merges + finalizes ----
    __threadfence();                          // publish parts (device scope)
    __syncthreads();                          // all stores issued before ticket
    if (t == 0) done_flag = atomicAdd(&tickets[h * 128 + qt], 1u);
    __syncthreads();
    if (done_flag == 1u) {
        __threadfence();                      // acquire partner's record
        const float* p0 = parts + (size_t)((h * 128 + qt) * 2) * PSTRIDE;
        const float* p1 = p0 + PSTRIDE;
        float* ob = out + (size_t)(h * N_TOK + qbase) * 32;
        for (int i = t; i < 1024; i += 256) {
            int r = i >> 5, d = i & 31;
            float o1  = p0[r * 32 + d]        + p1[r * 32 + d];
            float o2  = p0[1024 + r * 32 + d] + p1[1024 + r * 32 + d];
            float l1v = p0[2048 + r]          + p1[2048 + r];
            float l2v = p0[2080 + r]          + p1[2080 + r];
            ob[i] = o1 / l1v - LAMBDA_ * o2 / l2v;
        }
    }
}

extern "C" void kernel_launch(void* const* d_in, const int* in_sizes, int n_in,
                              void* d_out, int out_size, void* d_ws, size_t ws_size,
                              hipStream_t stream) {
    const float* x = (const float*)d_in[0];   // (1,128,32,32,32)
    const float* w = (const float*)d_in[1];   // (384,128)
    float* out = (float*)d_out;               // [h][n][32] flat (verified R1)

    unsigned short* qA = (unsigned short*)d_ws;               // 2 MB
    unsigned short* kB = qA + (size_t)NH * N_TOK * 64;        // 2 MB
    unsigned short* vT = kB + (size_t)NH * N_TOK * 64;        // 1 MB
    float* parts = (float*)(vT + (size_t)NH * 32 * N_TOK);    // 1024*2112*4B = 8.65 MB
    unsigned* tickets = (unsigned*)(parts + (size_t)1024 * PSTRIDE); // 512 ints

    qkv_kernel<<<512, 256, 0, stream>>>(x, w, qA, kB, vT, tickets);
    flash_kernel<<<1024, 256, 0, stream>>>(qA, kB, vT, parts, tickets, out);
}

// Round 14
// 145.430 us; speedup vs baseline: 1.8555x; 1.8555x over previous
//
#include <hip/hip_runtime.h>

#define N_TOK 4096
#define NH    4

typedef __attribute__((ext_vector_type(8))) short bf16x8;
typedef __attribute__((ext_vector_type(4))) short bf16x4;
typedef __attribute__((ext_vector_type(4))) float f32x4;

static constexpr float SCALE   = 0.17677669529663687f;  // 32^-0.5
static constexpr float QSCALE  = 0.25503632254435463f;  // SCALE * log2(e)
static constexpr float LAMBDA_ = 0.1f;
#define PSTRIDE 2112   // floats per (h,qt,ks) partial record (32q block)

// Manual pipeline sync (AITER pattern): retire only the OLDEST staged tile
// (vmcnt<=3 keeps the 3 younger global_load_lds in flight), drain own LDS
// reads (WAR), then barrier. Inline asm w/ memory clobber so the compiler
// cannot insert its own vmcnt(0) drain (the m131/m141 failure mode).
#define PIPE_BARRIER_KEEP3() asm volatile("s_waitcnt vmcnt(3) lgkmcnt(0)\ns_barrier" ::: "memory")
#define PIPE_BARRIER_DRAIN() asm volatile("s_waitcnt vmcnt(0) lgkmcnt(0)\ns_barrier" ::: "memory")

__device__ __forceinline__ unsigned short bf_rne(float f) {
    unsigned u = __float_as_uint(f);
    u += 0x7FFF + ((u >> 16) & 1);
    return (unsigned short)(u >> 16);
}

__device__ __forceinline__ void async_copy16(const unsigned short* g, unsigned short* l) {
    __builtin_amdgcn_global_load_lds(
        (const __attribute__((address_space(1))) void*)g,
        (__attribute__((address_space(3))) void*)l, 16, 0, 0);
}

// pack two fp32 into one dword of 2 bf16 (truncate): hi halves of (b,a)
__device__ __forceinline__ unsigned pack_hi(float a, float b) {
    return __builtin_amdgcn_perm(__float_as_uint(b), __float_as_uint(a), 0x07060302u);
}

// ---------------------------------------------------------------------------
// Kernel 1: qkv projection via MFMA with fused w-prep (R13-verified compute:
// QSCALE + hi/lo split in-register while building A-fragments).
//  qA[h][n][64] bf16: {q1hi q1lo q2hi q2lo} (QSCALE folded)   kB likewise
//  vT[h][kb=key/8][dim][8keys] bf16 RNE (granule-tiled)
// ---------------------------------------------------------------------------
__global__ __launch_bounds__(256) void qkv_kernel(
    const float* __restrict__ x, const float* __restrict__ w,
    unsigned short* __restrict__ qA, unsigned short* __restrict__ kB,
    unsigned short* __restrict__ vT)
{
    __shared__ __align__(16) float xf[16][132];
    __shared__ __align__(16) unsigned short xbh[16 * 136];
    __shared__ __align__(16) unsigned short xbl[16 * 136];
    __shared__ __align__(16) unsigned short qsh[2][16][64];
    __shared__ __align__(16) unsigned short ksh[2][16][64];
    __shared__ __align__(16) unsigned short vsh[2][32][16];

    const int t  = threadIdx.x;
    const int tg = blockIdx.x >> 1;
    const int rh = blockIdx.x & 1;            // row half: heads {2rh, 2rh+1}
    const int n0 = tg * 16;
    const int nhh = n0 >> 8, nw = (n0 >> 4) & 15;
    const int xbase = nhh * 2048 + nw * 64;

    #pragma unroll
    for (int k = 0; k < 8; ++k) {
        int idx = t + k * 256;
        int tok = idx & 15, ch = idx >> 4;
        xf[tok][ch] = x[(size_t)ch * 32768 + xbase + tok * 2];
    }
    __syncthreads();
    #pragma unroll
    for (int k = 0; k < 8; ++k) {
        int idx = t + k * 256;
        int tok = idx & 15, ch = idx >> 4;
        float f = xf[tok][ch];
        unsigned u = __float_as_uint(f);
        float lo = f - __uint_as_float(u & 0xFFFF0000u);
        xbh[tok * 136 + ch] = (unsigned short)(u >> 16);
        xbl[tok * 136 + ch] = (unsigned short)(__float_as_uint(lo) >> 16);
    }
    __syncthreads();

    const int lane = t & 63;
    const int m    = lane & 15;
    const int quad = lane >> 4;
    const int wv   = t >> 6;

    bf16x8 Bh[4], Bl[4];
    #pragma unroll
    for (int s = 0; s < 4; ++s) {
        Bh[s] = *(const bf16x8*)&xbh[m * 136 + s * 32 + quad * 8];
        Bl[s] = *(const bf16x8*)&xbl[m * 136 + s * 32 + quad * 8];
    }

    #pragma unroll
    for (int rt = 0; rt < 3; ++rt) {
        const int R0 = rh * 192 + wv * 48 + rt * 16;
        const float sq = ((R0 % 96) < 32) ? QSCALE : 1.0f;  // tile-uniform
        const float* wp = w + (size_t)(R0 + m) * 128;
        bf16x8 Ah[4], Al[4];
        #pragma unroll
        for (int s = 0; s < 4; ++s) {
            float4 wa = *(const float4*)(wp + s * 32 + quad * 8);
            float4 wb = *(const float4*)(wp + s * 32 + quad * 8 + 4);
            float f0 = wa.x * sq, f1 = wa.y * sq, f2 = wa.z * sq, f3 = wa.w * sq;
            float f4 = wb.x * sq, f5 = wb.y * sq, f6 = wb.z * sq, f7 = wb.w * sq;
            float g0 = f0 - __uint_as_float(__float_as_uint(f0) & 0xFFFF0000u);
            float g1 = f1 - __uint_as_float(__float_as_uint(f1) & 0xFFFF0000u);
            float g2 = f2 - __uint_as_float(__float_as_uint(f2) & 0xFFFF0000u);
            float g3 = f3 - __uint_as_float(__float_as_uint(f3) & 0xFFFF0000u);
            float g4 = f4 - __uint_as_float(__float_as_uint(f4) & 0xFFFF0000u);
            float g5 = f5 - __uint_as_float(__float_as_uint(f5) & 0xFFFF0000u);
            float g6 = f6 - __uint_as_float(__float_as_uint(f6) & 0xFFFF0000u);
            float g7 = f7 - __uint_as_float(__float_as_uint(f7) & 0xFFFF0000u);
            union { unsigned u[4]; bf16x8 v; } ah, al;
            ah.u[0] = pack_hi(f0, f1); ah.u[1] = pack_hi(f2, f3);
            ah.u[2] = pack_hi(f4, f5); ah.u[3] = pack_hi(f6, f7);
            al.u[0] = pack_hi(g0, g1); al.u[1] = pack_hi(g2, g3);
            al.u[2] = pack_hi(g4, g5); al.u[3] = pack_hi(g6, g7);
            Ah[s] = ah.v; Al[s] = al.v;
        }
        f32x4 C = {0, 0, 0, 0};
        #pragma unroll
        for (int s = 0; s < 4; ++s) {
            C = __builtin_amdgcn_mfma_f32_16x16x32_bf16(Ah[s], Bh[s], C, 0, 0, 0);
            C = __builtin_amdgcn_mfma_f32_16x16x32_bf16(Al[s], Bh[s], C, 0, 0, 0);
            C = __builtin_amdgcn_mfma_f32_16x16x32_bf16(Ah[s], Bl[s], C, 0, 0, 0);
        }
        #pragma unroll
        for (int i = 0; i < 4; ++i) {
            int R  = R0 + quad * 4 + i;
            int hh = R / 96;
            int rr = R - hh * 96;
            int hl = hh & 1;
            float f = C[i];
            if (rr < 64) {
                unsigned u = __float_as_uint(f);
                float lo = f - __uint_as_float(u & 0xFFFF0000u);
                unsigned short hi16 = (unsigned short)(u >> 16);
                unsigned short lo16 = (unsigned short)(__float_as_uint(lo) >> 16);
                int part = (rr & 31) >> 4, d = rr & 15;
                if (rr < 32) {
                    qsh[hl][m][part * 32 + d]      = hi16;
                    qsh[hl][m][part * 32 + d + 16] = lo16;
                } else {
                    ksh[hl][m][part * 32 + d]      = hi16;
                    ksh[hl][m][part * 32 + d + 16] = lo16;
                }
            } else {
                vsh[hl][rr - 64][m] = bf_rne(f);
            }
        }
    }
    __syncthreads();

    {   // qA/kB: 32 records (2 heads x 16 tok) x 8 granules of 16B
        int rec = t >> 3, ch8 = t & 7;
        int hl  = rec >> 4, i = rec & 15;
        int hh  = rh * 2 + hl;
        size_t base = ((size_t)hh * N_TOK + n0 + i) * 64 + ch8 * 8;
        *(uint4*)(qA + base) = *(const uint4*)&qsh[hl][i][ch8 * 8];
        *(uint4*)(kB + base) = *(const uint4*)&ksh[hl][i][ch8 * 8];
    }
    if (t < 128) {  // vT granule-tiled: [h][kb][dim][8]
        int hl = t >> 6, d = (t >> 1) & 31, half = t & 1;
        int hh = rh * 2 + hl;
        int kb = (n0 >> 3) + half;
        *(uint4*)(vT + (size_t)hh * 131072 + kb * 256 + d * 8) =
            *(const uint4*)&vsh[hl][d][half * 8];
    }
}

// ---------------------------------------------------------------------------
// Kernel 2: MFMA flash diff-attention v8 = R12's verified compute + 3-buffer
// depth-2 manual pipeline: per tile ONE `s_waitcnt vmcnt(3) lgkmcnt(0);
// s_barrier` (inline asm) retires only the stage issued 2 iterations ago —
// the fresh prefetches stay in flight across the barrier (no vmcnt(0) drain).
// Buffer safety: stage(t+2) reuses buf (t-1)%3, whose readers all finished
// before this tile's barrier (lgkmcnt(0) per wave + s_barrier).
// NO device-scope fences (R13 lesson). Partials -> parts; merge kernel 3.
// ---------------------------------------------------------------------------
__global__ __launch_bounds__(256, 2) void flash_kernel(
    const unsigned short* __restrict__ qA, const unsigned short* __restrict__ kB,
    const unsigned short* __restrict__ vT, float* __restrict__ parts)
{
    __shared__ __align__(16) unsigned short kv_sh[3][6144]; // 3 x 12 KB (K 8K + V 4K)
    __shared__ float Obuf[2][2][16][32];                    // [qt][br][r][d] 8 KB
    __shared__ float lbuf[2][2][16];

    const int t    = threadIdx.x;
    const int w    = t >> 6;
    const int lane = t & 63;
    const int m    = lane & 15;
    const int quad = lane >> 4;
    const int ks   = blockIdx.x & 1;
    const int qt   = (blockIdx.x >> 1) & 127;
    const int h    = blockIdx.x >> 8;
    const int qtile = w >> 1;                 // 0..1
    const int kh    = w & 1;                  // key half within tile
    const int qbase = qt * 32;

    const unsigned short* kBh = kB + (size_t)h * N_TOK * 64;
    const unsigned short* vTh = vT + (size_t)h * 131072;
    const int key0 = ks * 2048;

    auto stage = [&](int tile, int b) {
        const unsigned short* kben = kBh + (size_t)(key0 + tile * 64) * 64;
        const unsigned short* vben = vTh + (size_t)((key0 >> 3) + tile * 8) * 256;
        #pragma unroll
        for (int i = 0; i < 3; ++i) {
            int s = i * 256 + t;              // 0..767
            const unsigned short* src;
            if (s < 512) {                    // K: rec ml (0..63), XOR granule
                int ml = s >> 3, p = s & 7, c = p ^ (ml & 7);
                src = kben + ml * 64 + c * 8;
            } else {                          // V: granule (kb_l, dim)
                int s2 = s - 512;
                int kb_l = s2 >> 5, d = s2 & 31;
                src = vben + kb_l * 256 + d * 8;
            }
            async_copy16(src, &kv_sh[b][s * 8]);
        }
    };

    // q fragments FIRST (their vmcnt retires before the staged tiles')
    const unsigned short* qrec = qA + (size_t)(h * N_TOK + qbase + qtile * 16 + m) * 64;
    const bf16x8 zz = {0,0,0,0,0,0,0,0};
    bf16x8 Bq1h = *(const bf16x8*)(qrec + (quad & 1) * 8);
    bf16x8 Bq2h = *(const bf16x8*)(qrec + 32 + (quad & 1) * 8);
    bf16x8 Bq1l = (quad < 2) ? *(const bf16x8*)(qrec + 16 + quad * 8) : zz;
    bf16x8 Bq2l = (quad < 2) ? *(const bf16x8*)(qrec + 48 + quad * 8) : zz;

    stage(0, 0);
    stage(1, 1);

    for (int i = t; i < 2048; i += 256) ((float*)Obuf)[i] = 0.f;
    if (t < 64) ((float*)lbuf)[t] = 0.f;

    f32x4 O1a = {0,0,0,0}, O1b = {0,0,0,0}, O2a = {0,0,0,0}, O2b = {0,0,0,0};
    float l1 = 0.f, l2 = 0.f;

    const int ml0 = kh * 32 + m, ml1 = ml0 + 16;
    const int a1o0 = ml0 * 64 + ((quad)     ^ (ml0 & 7)) * 8;
    const int a2o0 = ml0 * 64 + ((4 + quad) ^ (ml0 & 7)) * 8;
    const int a1o1 = ml1 * 64 + ((quad)     ^ (ml1 & 7)) * 8;
    const int a2o1 = ml1 * 64 + ((4 + quad) ^ (ml1 & 7)) * 8;
    const int kbl0 = kh * 4 + (quad >> 1);
    const int v0o0 = 4096 + (kbl0 * 32 + m)      * 8 + (quad & 1) * 4;
    const int v1o0 = 4096 + (kbl0 * 32 + 16 + m) * 8 + (quad & 1) * 4;
    const int v0o1 = v0o0 + 512;
    const int v1o1 = v1o0 + 512;

    int bc = 0, bs = 2;                       // current buf / stage-dest buf
    #pragma unroll 1
    for (int tile = 0; tile < 32; ++tile) {
        if (tile < 31) { PIPE_BARRIER_KEEP3(); } else { PIPE_BARRIER_DRAIN(); }
        if (tile + 2 < 32) stage(tile + 2, bs);

        const unsigned short* buf = kv_sh[bc];
        bf16x8 K1_0 = *(const bf16x8*)(buf + a1o0);
        bf16x8 K2_0 = *(const bf16x8*)(buf + a2o0);
        bf16x8 K1_1 = *(const bf16x8*)(buf + a1o1);
        bf16x8 K2_1 = *(const bf16x8*)(buf + a2o1);

        f32x4 sA1 = {0,0,0,0}, sA2 = {0,0,0,0};
        f32x4 sB1 = {0,0,0,0}, sB2 = {0,0,0,0};
        sA1 = __builtin_amdgcn_mfma_f32_16x16x32_bf16(K1_0, Bq1h, sA1, 0, 0, 0);
        sB1 = __builtin_amdgcn_mfma_f32_16x16x32_bf16(K1_1, Bq1h, sB1, 0, 0, 0);
        sA1 = __builtin_amdgcn_mfma_f32_16x16x32_bf16(K1_0, Bq1l, sA1, 0, 0, 0);
        sB1 = __builtin_amdgcn_mfma_f32_16x16x32_bf16(K1_1, Bq1l, sB1, 0, 0, 0);
        sA2 = __builtin_amdgcn_mfma_f32_16x16x32_bf16(K2_0, Bq2h, sA2, 0, 0, 0);
        sB2 = __builtin_amdgcn_mfma_f32_16x16x32_bf16(K2_1, Bq2h, sB2, 0, 0, 0);
        sA2 = __builtin_amdgcn_mfma_f32_16x16x32_bf16(K2_0, Bq2l, sA2, 0, 0, 0);
        sB2 = __builtin_amdgcn_mfma_f32_16x16x32_bf16(K2_1, Bq2l, sB2, 0, 0, 0);

        float pa0 = __builtin_amdgcn_exp2f(sA1[0]), pa1 = __builtin_amdgcn_exp2f(sA1[1]);
        float pa2 = __builtin_amdgcn_exp2f(sA1[2]), pa3 = __builtin_amdgcn_exp2f(sA1[3]);
        float pb0 = __builtin_amdgcn_exp2f(sB1[0]), pb1 = __builtin_amdgcn_exp2f(sB1[1]);
        float pb2 = __builtin_amdgcn_exp2f(sB1[2]), pb3 = __builtin_amdgcn_exp2f(sB1[3]);
        float qa0 = __builtin_amdgcn_exp2f(sA2[0]), qa1 = __builtin_amdgcn_exp2f(sA2[1]);
        float qa2 = __builtin_amdgcn_exp2f(sA2[2]), qa3 = __builtin_amdgcn_exp2f(sA2[3]);
        float qb0 = __builtin_amdgcn_exp2f(sB2[0]), qb1 = __builtin_amdgcn_exp2f(sB2[1]);
        float qb2 = __builtin_amdgcn_exp2f(sB2[2]), qb3 = __builtin_amdgcn_exp2f(sB2[3]);
        l1 += (pa0 + pa1) + (pa2 + pa3) + (pb0 + pb1) + (pb2 + pb3);
        l2 += (qa0 + qa1) + (qa2 + qa3) + (qb0 + qb1) + (qb2 + qb3);
        union { unsigned u[2]; bf16x4 v; } cA1, cB1, cA2, cB2;
        cA1.u[0] = pack_hi(pa0, pa1); cA1.u[1] = pack_hi(pa2, pa3);
        cB1.u[0] = pack_hi(pb0, pb1); cB1.u[1] = pack_hi(pb2, pb3);
        cA2.u[0] = pack_hi(qa0, qa1); cA2.u[1] = pack_hi(qa2, qa3);
        cB2.u[0] = pack_hi(qb0, qb1); cB2.u[1] = pack_hi(qb2, qb3);

        bf16x4 V00 = *(const bf16x4*)(buf + v0o0);
        bf16x4 V10 = *(const bf16x4*)(buf + v1o0);
        bf16x4 V01 = *(const bf16x4*)(buf + v0o1);
        bf16x4 V11 = *(const bf16x4*)(buf + v1o1);

        O1a = __builtin_amdgcn_mfma_f32_16x16x16bf16_1k(cA1.v, V00, O1a, 0, 0, 0);
        O1b = __builtin_amdgcn_mfma_f32_16x16x16bf16_1k(cA1.v, V10, O1b, 0, 0, 0);
        O2a = __builtin_amdgcn_mfma_f32_16x16x16bf16_1k(cA2.v, V00, O2a, 0, 0, 0);
        O2b = __builtin_amdgcn_mfma_f32_16x16x16bf16_1k(cA2.v, V10, O2b, 0, 0, 0);
        O1a = __builtin_amdgcn_mfma_f32_16x16x16bf16_1k(cB1.v, V01, O1a, 0, 0, 0);
        O1b = __builtin_amdgcn_mfma_f32_16x16x16bf16_1k(cB1.v, V11, O1b, 0, 0, 0);
        O2a = __builtin_amdgcn_mfma_f32_16x16x16bf16_1k(cB2.v, V01, O2a, 0, 0, 0);
        O2b = __builtin_amdgcn_mfma_f32_16x16x16bf16_1k(cB2.v, V11, O2b, 0, 0, 0);

        bc = (bc == 2) ? 0 : bc + 1;
        bs = (bs == 2) ? 0 : bs + 1;
    }

    l1 += __shfl_xor(l1, 16, 64); l1 += __shfl_xor(l1, 32, 64);
    l2 += __shfl_xor(l2, 16, 64); l2 += __shfl_xor(l2, 32, 64);
    if (lane < 16) {
        atomicAdd(&lbuf[qtile][0][m], l1);
        atomicAdd(&lbuf[qtile][1][m], l2);
    }
    #pragma unroll
    for (int i = 0; i < 4; ++i) {
        int r = quad * 4 + i;
        atomicAdd(&Obuf[qtile][0][r][m],      O1a[i]);
        atomicAdd(&Obuf[qtile][0][r][16 + m], O1b[i]);
        atomicAdd(&Obuf[qtile][1][r][m],      O2a[i]);
        atomicAdd(&Obuf[qtile][1][r][16 + m], O2b[i]);
    }
    __syncthreads();

    // store partial record: [O1 1024][O2 1024][l1 32][l2 32]
    float* dst = parts + (size_t)((h * 128 + qt) * 2 + ks) * PSTRIDE;
    for (int i = t; i < 1024; i += 256) {
        int r = i >> 5, d = i & 31;
        int qtl = r >> 4, rl = r & 15;
        dst[i]        = Obuf[qtl][0][rl][d];
        dst[1024 + i] = Obuf[qtl][1][rl][d];
    }
    if (t < 32) {
        int qtl = t >> 4, rl = t & 15;
        dst[2048 + t] = lbuf[qtl][0][rl];
        dst[2080 + t] = lbuf[qtl][1][rl];
    }
}

// ---------------------------------------------------------------------------
// Kernel 3: split-K merge + finalize (verbatim R12 — separate dispatch; a
// fused fence-based merge costs 150us on this 8-XCD part, see R13).
// ---------------------------------------------------------------------------
__global__ __launch_bounds__(256) void merge_kernel(
    const float* __restrict__ parts, float* __restrict__ out)
{
    int idx = blockIdx.x * 256 + threadIdx.x;     // 524288
    int row = idx >> 5, d = idx & 31;
    int h = row >> 12, n = row & 4095;
    int qt = n >> 5, r = n & 31;
    const float* p0 = parts + (size_t)((h * 128 + qt) * 2) * PSTRIDE;
    const float* p1 = p0 + PSTRIDE;
    float o1 = p0[r * 32 + d]        + p1[r * 32 + d];
    float o2 = p0[1024 + r * 32 + d] + p1[1024 + r * 32 + d];
    float l1 = p0[2048 + r]          + p1[2048 + r];
    float l2 = p0[2080 + r]          + p1[2080 + r];
    out[idx] = o1 / l1 - LAMBDA_ * o2 / l2;
}

extern "C" void kernel_launch(void* const* d_in, const int* in_sizes, int n_in,
                              void* d_out, int out_size, void* d_ws, size_t ws_size,
                              hipStream_t stream) {
    const float* x = (const float*)d_in[0];   // (1,128,32,32,32)
    const float* w = (const float*)d_in[1];   // (384,128)
    float* out = (float*)d_out;               // [h][n][32] flat (verified R1)

    unsigned short* qA = (unsigned short*)d_ws;               // 2 MB
    unsigned short* kB = qA + (size_t)NH * N_TOK * 64;        // 2 MB
    unsigned short* vT = kB + (size_t)NH * N_TOK * 64;        // 1 MB
    float* parts = (float*)(vT + (size_t)NH * 32 * N_TOK);    // 1024*2112*4B = 8.65 MB

    qkv_kernel<<<512, 256, 0, stream>>>(x, w, qA, kB, vT);
    flash_kernel<<<1024, 256, 0, stream>>>(qA, kB, vT, parts);
    merge_kernel<<<2048, 256, 0, stream>>>(parts, out);
}